// Round 2
// 685.115 us; speedup vs baseline: 1.0452x; 1.0452x over previous
//
#include <hip/hip_runtime.h>
#include <cstdint>

// SparseMoE on MI355X (gfx950). fp32 inputs. B=2,S=2048 -> NTOK=4096 tokens,
// D=1024, E=8, H=4096, top_k=2.
// R2 (recovery round): R0's proven 128x128 grouped GEMM with ONE change —
// 2-phase double-buffered K-loop (STAGE(next) || compute(cur), one barrier
// per K-step) using 64 KiB STATIC LDS. No dynamic LDS, no hipFuncSetAttribute,
// no register-pressure change — minimizes crash surface vs the failed R1.

#define DEV __device__ __forceinline__

typedef __attribute__((ext_vector_type(8))) short short8;   // 8 x bf16
typedef __attribute__((ext_vector_type(4))) float floatx4;  // MFMA accumulator

constexpr int D_ = 1024, E_ = 8, H_ = 4096;
constexpr int NTOK = 4096;
constexpr int CAP  = 4096;
constexpr int TOTSLOT = NTOK * 2;

// ---- workspace layout (bytes); ~160.3 MB, proven available ----
constexpr size_t O_COUNT = 0;
constexpr size_t O_OFFS  = 64;
constexpr size_t O_BTOK  = 128;
constexpr size_t O_BGATE = O_BTOK  + (size_t)E_ * CAP * 4;
constexpr size_t O_PAIR  = O_BGATE + (size_t)E_ * CAP * 4;
constexpr size_t O_XG    = (O_PAIR + (size_t)NTOK * 2 * 4 + 255) & ~(size_t)255;
constexpr size_t O_HBUF  = O_XG   + (size_t)TOTSLOT * D_ * 2;  // 16 MB
constexpr size_t O_YBUF  = O_HBUF + (size_t)TOTSLOT * H_ * 2;  // 64 MB
constexpr size_t O_WT    = O_YBUF + (size_t)TOTSLOT * D_ * 2;  // 16 MB
constexpr size_t WS_NEED = O_WT   + (size_t)E_ * D_ * H_ * 2;  // + 64 MB

DEV float b2f(unsigned short u) {
    union { unsigned int i; float f; } v; v.i = ((unsigned int)u) << 16; return v.f;
}
DEV unsigned int f2b(float f) {  // round-to-nearest-even, low 16 bits
    union { float f; unsigned int i; } v; v.f = f;
    unsigned int r = v.i + 0x7fffu + ((v.i >> 16) & 1u);
    return (r >> 16) & 0xffffu;
}
DEV float gelu_tanh(float x) {
    float u = 0.7978845608028654f * (x + 0.044715f * x * x * x);
    u = fminf(fmaxf(u, -20.f), 20.f);
    float e = __expf(2.f * u);
    float t = (e - 1.f) / (e + 1.f);
    return 0.5f * x * (1.f + t);
}

// async global->LDS, 16 B per lane (dest = wave-uniform base + lane*16)
typedef __attribute__((address_space(3))) unsigned int lds_u32_t;
typedef const __attribute__((address_space(1))) unsigned int g_u32_t;
DEV void gload16(const unsigned short* g, const unsigned short* l) {
    __builtin_amdgcn_global_load_lds((g_u32_t*)(size_t)g,
                                     (lds_u32_t*)(unsigned int)(size_t)l, 16, 0, 0);
}

// ---------------------------------------------------------------------------
__global__ __launch_bounds__(64) void zero_counts(int* counts) {
    if (threadIdx.x < E_) counts[threadIdx.x] = 0;
}

// Router: one wave per token, fp64 accumulation (minimizes top-k flips vs the
// np fp32 reference — the dominant correctness risk; proven R2/R3).
__global__ __launch_bounds__(256) void router_kernel(
    const float* __restrict__ x, const float* __restrict__ noise,
    const float* __restrict__ w_route, const float* __restrict__ b_route,
    const float* __restrict__ w_noise, const float* __restrict__ b_noise,
    float* __restrict__ out,  // gate1 at element offset NTOK*D_
    int* counts, int* btok, float* bgate, int* pairs)
{
    int wave = threadIdx.x >> 6, lane = threadIdx.x & 63;
    int t = blockIdx.x * 4 + wave;

    double racc[E_], nacc[E_];
#pragma unroll
    for (int e = 0; e < E_; e++) { racc[e] = 0.0; nacc[e] = 0.0; }

#pragma unroll 4
    for (int i = 0; i < D_ / 64; i++) {
        int j = i * 64 + lane;
        float xv = x[(size_t)t * D_ + j];
        const float* wr = w_route + (size_t)j * E_;
        const float* wn = w_noise + (size_t)j * E_;
        float4 a0 = ((const float4*)wr)[0], a1 = ((const float4*)wr)[1];
        float4 c0 = ((const float4*)wn)[0], c1 = ((const float4*)wn)[1];
        const float rv[8] = {a0.x,a0.y,a0.z,a0.w,a1.x,a1.y,a1.z,a1.w};
        const float nv[8] = {c0.x,c0.y,c0.z,c0.w,c1.x,c1.y,c1.z,c1.w};
#pragma unroll
        for (int e = 0; e < E_; e++) {
            racc[e] += (double)(xv * rv[e]);
            nacc[e] += (double)(xv * nv[e]);
        }
    }
#pragma unroll
    for (int off = 32; off > 0; off >>= 1)
#pragma unroll
        for (int e = 0; e < E_; e++) {
            racc[e] += __shfl_down(racc[e], off);
            nacc[e] += __shfl_down(nacc[e], off);
        }

    if (lane == 0) {
        double nz[E_];
#pragma unroll
        for (int e = 0; e < E_; e++) {
            double lg = racc[e] + (double)b_route[e];
            double nl = nacc[e] + (double)b_noise[e];
            double sp = (nl > 0.0) ? nl + log1p(exp(-nl)) : log1p(exp(nl));
            nz[e] = lg + (double)noise[(size_t)t * E_ + e] * sp;
        }
        double mx = nz[0];
#pragma unroll
        for (int e = 1; e < E_; e++) mx = fmax(mx, nz[e]);
        double se = 0.0, ex[E_];
#pragma unroll
        for (int e = 0; e < E_; e++) { ex[e] = exp(nz[e] - mx); se += ex[e]; }
#pragma unroll
        for (int e = 0; e < E_; e++)
            out[(size_t)NTOK * D_ + (size_t)t * E_ + e] = (float)(ex[e] / se);
        // top-2 (strict > keeps lower index on ties, matching lax.top_k)
        double v0 = -1e300, v1 = -1e300; int i0 = 0, i1 = 0;
#pragma unroll
        for (int e = 0; e < E_; e++) {
            double v = nz[e];
            if (v > v0) { v1 = v0; i1 = i0; v0 = v; i0 = e; }
            else if (v > v1) { v1 = v; i1 = e; }
        }
        double g0 = 1.0 / (1.0 + exp(v1 - v0));
        float  g1 = (float)(1.0 - g0);
        int l0 = atomicAdd(&counts[i0], 1);
        int l1 = atomicAdd(&counts[i1], 1);
        btok[i0 * CAP + l0] = t;  bgate[i0 * CAP + l0] = (float)g0;
        btok[i1 * CAP + l1] = t;  bgate[i1 * CAP + l1] = g1;
        pairs[2 * t]     = (i0 << 16) | l0;
        pairs[2 * t + 1] = (i1 << 16) | l1;
    }
}

__global__ __launch_bounds__(64) void offsets_kernel(const int* counts, int* offs) {
    if (threadIdx.x == 0) {
        int a = 0;
        for (int e = 0; e < E_; e++) { offs[e] = a; a += counts[e]; }
        offs[E_] = a;
    }
}

// Scatter x rows (fp32 -> bf16) to both selected slots. One block per token:
// x read exactly once, coalesced; no dead blocks.
__global__ __launch_bounds__(256) void gather_x(
    const float* __restrict__ x, const int* __restrict__ pairs,
    const int* __restrict__ offs, unsigned short* __restrict__ xg)
{
    int t = blockIdx.x;
    int c = threadIdx.x * 4;
    float4 v = *(const float4*)(x + (size_t)t * D_ + c);
    uint2 o;
    o.x = f2b(v.x) | (f2b(v.y) << 16);
    o.y = f2b(v.z) | (f2b(v.w) << 16);
    int p0 = pairs[2 * t], p1 = pairs[2 * t + 1];
    size_t r0 = (size_t)(offs[p0 >> 16] + (p0 & 0xffff)) * D_;
    size_t r1 = (size_t)(offs[p1 >> 16] + (p1 & 0xffff)) * D_;
    *(uint2*)(xg + r0 + c) = o;
    *(uint2*)(xg + r1 + c) = o;
}

// transpose+convert: w [E][K][N] fp32 -> wT [E][N][K] bf16. 64x64 LDS tiles.
__global__ __launch_bounds__(256) void transpose_w(
    const float* __restrict__ w, unsigned short* __restrict__ wT, int K, int N)
{
    __shared__ unsigned short t[64][65];
    const int e  = blockIdx.z;
    const int k0 = blockIdx.y * 64;
    const int n0 = blockIdx.x * 64;
    const int r  = threadIdx.x >> 2;          // 0..63
    const int c4 = (threadIdx.x & 3) * 16;    // 0,16,32,48
    const float* src = w + ((size_t)e * K + k0 + r) * N + n0 + c4;
#pragma unroll
    for (int i = 0; i < 4; i++) {
        float4 v = ((const float4*)src)[i];
        t[r][c4 + 4*i + 0] = (unsigned short)f2b(v.x);
        t[r][c4 + 4*i + 1] = (unsigned short)f2b(v.y);
        t[r][c4 + 4*i + 2] = (unsigned short)f2b(v.z);
        t[r][c4 + 4*i + 3] = (unsigned short)f2b(v.w);
    }
    __syncthreads();
    unsigned short* dstp = wT + ((size_t)e * N + n0 + r) * K + k0 + c4;
    unsigned short tmp[16];
#pragma unroll
    for (int i = 0; i < 16; i++) tmp[i] = t[c4 + i][r];
#pragma unroll
    for (int h = 0; h < 2; h++) {
        uint4 pk;
        pk.x = (unsigned int)tmp[8*h+0] | ((unsigned int)tmp[8*h+1] << 16);
        pk.y = (unsigned int)tmp[8*h+2] | ((unsigned int)tmp[8*h+3] << 16);
        pk.z = (unsigned int)tmp[8*h+4] | ((unsigned int)tmp[8*h+5] << 16);
        pk.w = (unsigned int)tmp[8*h+6] | ((unsigned int)tmp[8*h+7] << 16);
        ((uint4*)dstp)[h] = pk;
    }
}

// ---- grouped GEMM, 128x128 tile + 2-phase double-buffered K-loop -----------
// 4 waves (2x2 of 64x64), 16x16x32 bf16 MFMA, BK=64. Per K-step: issue next
// tile's global_load_lds into buf^1 FIRST, then ds_read+MFMA on buf, then ONE
// __syncthreads (compiler emits vmcnt(0)+lgkmcnt(0) drain before s_barrier).
// Load latency elapses under compute instead of being serially exposed.
// XOR k-group swizzle via pre-swizzled global source (0 conflicts measured).
// XCD mapping unchanged from the proven R0 kernel.
template <int KD, int ND, bool FC>
__global__ __launch_bounds__(256) void moe_gemm3(
    const unsigned short* __restrict__ A,    // [TOTSLOT][KD] bf16 (xg or hbuf)
    const unsigned short* __restrict__ wT,   // [E][ND][KD] bf16
    const float* __restrict__ bias32,        // [E][ND] fp32 (direct input)
    unsigned short* __restrict__ dst,        // [TOTSLOT][ND] bf16
    const int* __restrict__ counts, const int* __restrict__ offs,
    const float* __restrict__ bgate)
{
    const int lin = blockIdx.x;
    const int xcd = lin & 7, slot = lin >> 3;
    int e, mt, nt;
    if (FC) {            // ND=4096: 32 n-tiles, 4 per XCD, nsub fastest
        nt = xcd * 4 + (slot & 3);
        mt = (slot >> 2) & 31;
        e  = slot >> 7;
    } else {             // ND=1024: 8 n-tiles, 1 per XCD, m fastest
        nt = xcd;
        mt = slot & 31;
        e  = slot >> 5;
    }
    const int cnt = counts[e];
    const int m0 = mt * 128;
    if (m0 >= cnt) return;
    const int n0 = nt * 128;
    const int off = offs[e];

    // [2 buffers][A 128x64 | B 128x64] = 64 KiB static LDS
    __shared__ unsigned short smem[2][2 * 128 * 64];
    constexpr int BOFF = 128 * 64;           // B offset within a buffer

    const int tid = threadIdx.x;
    const int waveid = tid >> 6, lane = tid & 63;
    const int sr = lane >> 3;            // row within 8-row chunk
    const int g  = lane & 7;             // k-group slot in LDS
    const int scol = ((g ^ sr) * 8);     // XOR-swizzled global k-offset

    const unsigned short* aAddr[4];
    const unsigned short* bAddr[4];
#pragma unroll
    for (int c = 0; c < 4; c++) {
        int ar = m0 + (waveid * 4 + c) * 8 + sr;
        if (ar > cnt - 1) ar = cnt - 1;
        aAddr[c] = A + (size_t)(off + ar) * KD + scol;
        int br = n0 + (waveid * 4 + c) * 8 + sr;
        bAddr[c] = wT + ((size_t)e * ND + br) * KD + scol;
    }
    const int ldsChunk = (waveid * 4) * 512;

    const int wm = (waveid & 1) * 64, wn = (waveid >> 1) * 64;
    const int lrow = lane & 15, quad = lane >> 4;

    floatx4 acc[4][4];
#pragma unroll
    for (int fm = 0; fm < 4; fm++)
#pragma unroll
        for (int fn = 0; fn < 4; fn++) acc[fm][fn] = (floatx4)0.f;

    const int nk = KD / 64;

    // prologue: stage K-tile 0 into buffer 0
#pragma unroll
    for (int c = 0; c < 4; c++) {
        gload16(aAddr[c], &smem[0][ldsChunk + c * 512]);
        gload16(bAddr[c], &smem[0][BOFF + ldsChunk + c * 512]);
    }
    __syncthreads();

#pragma unroll 2
    for (int t = 0; t < nk; ++t) {
        const int cur = t & 1;
        // phase A: issue next K-tile's async loads into the other buffer
        if (t + 1 < nk) {
            const int k0 = (t + 1) * 64;
#pragma unroll
            for (int c = 0; c < 4; c++) {
                gload16(aAddr[c] + k0, &smem[cur ^ 1][ldsChunk + c * 512]);
                gload16(bAddr[c] + k0, &smem[cur ^ 1][BOFF + ldsChunk + c * 512]);
            }
        }
        // phase B: compute on current buffer (load latency hides under this)
        const unsigned short* As = &smem[cur][0];
        const unsigned short* Bs = &smem[cur][BOFF];
#pragma unroll
        for (int ks = 0; ks < 2; ks++) {
            short8 af[4], bfr[4];
#pragma unroll
            for (int f = 0; f < 4; f++) {
                int Ra = wm + f * 16 + lrow;
                int Rb = wn + f * 16 + lrow;
                af[f]  = *(const short8*)&As[Ra * 64 + ((ks * 4 + quad) ^ (Ra & 7)) * 8];
                bfr[f] = *(const short8*)&Bs[Rb * 64 + ((ks * 4 + quad) ^ (Rb & 7)) * 8];
            }
#pragma unroll
            for (int fm = 0; fm < 4; fm++)
#pragma unroll
                for (int fn = 0; fn < 4; fn++)
                    acc[fm][fn] = __builtin_amdgcn_mfma_f32_16x16x32_bf16(
                        af[fm], bfr[fn], acc[fm][fn], 0, 0, 0);
        }
        // single drain per K-step: vmcnt(0)+lgkmcnt(0)+barrier, then flip
        __syncthreads();
    }

    // Epilogue. C/D layout: col = lane&15, row = quad*4 + reg.
    const int gc = n0 + wn + lrow;
    float bcol[4];
#pragma unroll
    for (int fn = 0; fn < 4; fn++) bcol[fn] = bias32[(size_t)e * ND + gc + fn * 16];

#pragma unroll
    for (int fm = 0; fm < 4; fm++) {
        int srow0 = m0 + wm + fm * 16 + quad * 4;
#pragma unroll
        for (int r = 0; r < 4; r++) {
            int srow = srow0 + r;
            if (srow < cnt) {
                size_t base = (size_t)(off + srow) * ND;
                if (FC) {
#pragma unroll
                    for (int fn = 0; fn < 4; fn++) {
                        float v = acc[fm][fn][r] + bcol[fn];
                        dst[base + gc + fn * 16] = (unsigned short)f2b(gelu_tanh(v));
                    }
                } else {
                    float gt = bgate[e * CAP + srow];
#pragma unroll
                    for (int fn = 0; fn < 4; fn++) {
                        float v = (acc[fm][fn][r] + bcol[fn]) * gt;
                        dst[base + gc + fn * 16] = (unsigned short)f2b(v);
                    }
                }
            }
        }
    }
}

// out[t] = ybuf[slot0(t)] + ybuf[slot1(t)]  (gates already applied), fp32 out
__global__ __launch_bounds__(256) void combine_kernel(
    const unsigned short* __restrict__ ybuf, const int* __restrict__ pairs,
    const int* __restrict__ offs, float* __restrict__ out)
{
    int t = blockIdx.x;
    int p0 = pairs[2 * t], p1 = pairs[2 * t + 1];
    size_t r0 = (size_t)(offs[p0 >> 16] + (p0 & 0xffff)) * D_;
    size_t r1 = (size_t)(offs[p1 >> 16] + (p1 & 0xffff)) * D_;
    int c = threadIdx.x * 4;
    uint2 a = *(const uint2*)(ybuf + r0 + c);
    uint2 b = *(const uint2*)(ybuf + r1 + c);
    float4 o;
    o.x = b2f((unsigned short)(a.x & 0xffffu)) + b2f((unsigned short)(b.x & 0xffffu));
    o.y = b2f((unsigned short)(a.x >> 16))     + b2f((unsigned short)(b.x >> 16));
    o.z = b2f((unsigned short)(a.y & 0xffffu)) + b2f((unsigned short)(b.y & 0xffffu));
    o.w = b2f((unsigned short)(a.y >> 16))     + b2f((unsigned short)(b.y >> 16));
    *(float4*)(out + (size_t)t * D_ + c) = o;
}

// ---------------------------------------------------------------------------
extern "C" void kernel_launch(void* const* d_in, const int* in_sizes, int n_in,
                              void* d_out, int out_size, void* d_ws, size_t ws_size,
                              hipStream_t stream) {
    if (ws_size < WS_NEED) return;  // diagnostic: output stays 0

    const float* x       = (const float*)d_in[0];
    const float* noise   = (const float*)d_in[1];
    const float* w_route = (const float*)d_in[2];
    const float* b_route = (const float*)d_in[3];
    const float* w_noise = (const float*)d_in[4];
    const float* b_noise = (const float*)d_in[5];
    const float* w_fc    = (const float*)d_in[6];
    const float* b_fc    = (const float*)d_in[7];
    const float* w_proj  = (const float*)d_in[8];
    const float* b_proj  = (const float*)d_in[9];

    char* ws = (char*)d_ws;
    int*   counts = (int*)(ws + O_COUNT);
    int*   offs   = (int*)(ws + O_OFFS);
    int*   btok   = (int*)(ws + O_BTOK);
    float* bgate  = (float*)(ws + O_BGATE);
    int*   pairs  = (int*)(ws + O_PAIR);
    unsigned short* xg   = (unsigned short*)(ws + O_XG);
    unsigned short* hbuf = (unsigned short*)(ws + O_HBUF);
    unsigned short* ybuf = (unsigned short*)(ws + O_YBUF);
    unsigned short* wT   = (unsigned short*)(ws + O_WT);

    zero_counts<<<dim3(1), dim3(64), 0, stream>>>(counts);
    router_kernel<<<dim3(NTOK / 4), dim3(256), 0, stream>>>(
        x, noise, w_route, b_route, w_noise, b_noise, (float*)d_out,
        counts, btok, bgate, pairs);
    offsets_kernel<<<dim3(1), dim3(64), 0, stream>>>(counts, offs);
    gather_x<<<dim3(NTOK), dim3(256), 0, stream>>>(x, pairs, offs, xg);

    // FC: w_fc [E][D][H] -> wT [E][H][D]
    transpose_w<<<dim3(H_ / 64, D_ / 64, E_), dim3(256), 0, stream>>>(w_fc, wT, D_, H_);
    moe_gemm3<D_, H_, true><<<dim3(8 * 32 * 32), dim3(256), 0, stream>>>(
        xg, wT, b_fc, hbuf, counts, offs, bgate);

    // proj: w_proj [E][H][D] -> wT [E][D][H]
    transpose_w<<<dim3(D_ / 64, H_ / 64, E_), dim3(256), 0, stream>>>(w_proj, wT, H_, D_);
    moe_gemm3<H_, D_, false><<<dim3(8 * 32 * 8), dim3(256), 0, stream>>>(
        hbuf, wT, b_proj, ybuf, counts, offs, bgate);

    combine_kernel<<<dim3(NTOK), dim3(256), 0, stream>>>(ybuf, pairs, offs, (float*)d_out);
}